// Round 1
// baseline (1140.292 us; speedup 1.0000x reference)
//
#include <hip/hip_runtime.h>
#include <hip/hip_bf16.h>

#define S_DIM 2048
#define R_DIM 512
#define C_DIM 64
#define LN_EPSF 1e-5f
#define EPSF 1e-10f
#define INFF 1000000000.0f

// ---------- helpers ----------
__device__ __forceinline__ float wave_sum64(float v) {
#pragma unroll
  for (int m = 1; m < 64; m <<= 1) v += __shfl_xor(v, m, 64);
  return v;
}

__device__ __forceinline__ float bf2f(unsigned short u) {
  return __uint_as_float(((unsigned int)u) << 16);
}

// ---------- kernel A: LN + k/v + q_pool partials (+ optional x store) ----------
// grid: R * (S/32) blocks, 256 threads (4 waves), each wave does 8 positions of
// one fixed r. lane = channel c.
template <bool STORE_X>
__global__ __launch_bounds__(256) void kA(
    const float* __restrict__ m_in, const float* __restrict__ mask,
    const float* __restrict__ ln_w, const float* __restrict__ ln_b,
    const float* __restrict__ wk, const float* __restrict__ wv,
    __hip_bfloat16* __restrict__ x_ws, __hip_bfloat16* __restrict__ k_ws,
    __hip_bfloat16* __restrict__ v_ws, float* __restrict__ qnum,
    float* __restrict__ msum) {
  const int tid = threadIdx.x;
  const int w = tid >> 6;
  const int lane = tid & 63;
  const int r = blockIdx.x & (R_DIM - 1);
  const int chunk = blockIdx.x >> 9;  // 64 chunks of 32 s each
  const int s_base = chunk * 32;

  const float lw = ln_w[lane];
  const float lb = ln_b[lane];

  // kv matvec setup: lane = j + 16*q4 ; j<8 -> k col j, j>=8 -> v col j-8.
  // lane accumulates partial dot over c = q4*16 .. q4*16+15, then xor-reduce.
  const int j = lane & 15;
  const int q4 = lane >> 4;
  const int jj = j & 7;
  const float* wmat = (j < 8) ? wk : wv;
  float wreg[16];
#pragma unroll
  for (int cc = 0; cc < 16; ++cc) wreg[cc] = wmat[(q4 * 16 + cc) * 8 + jj];

  float qacc = 0.f;  // per-lane (=channel) masked sum of x over this block's s
  float macc = 0.f;  // mask sum (uniform across lanes)

  for (int it = 0; it < 8; ++it) {
    const int s = s_base + it * 4 + w;
    const size_t pos = (size_t)s * R_DIM + r;
    const float xv = m_in[pos * 64 + lane];
    const float mk = mask[pos];
    // LayerNorm over the 64 channels (one wave = one position)
    const float mu = wave_sum64(xv) * (1.f / 64.f);
    const float d = xv - mu;
    const float var = wave_sum64(d * d) * (1.f / 64.f);
    const float xn = fmaf(d * rsqrtf(var + LN_EPSF), lw, lb);

    qacc = fmaf(xn, mk, qacc);
    macc += mk;

    if (STORE_X) x_ws[pos * 64 + lane] = __float2bfloat16(xn);

    // k,v: 16 outputs (8 k + 8 v), 4-way partial + xor reduce
    float acc = 0.f;
#pragma unroll
    for (int cc = 0; cc < 16; ++cc) {
      const float xc = __shfl(xn, q4 * 16 + cc, 64);
      acc = fmaf(xc, wreg[cc], acc);
    }
    acc += __shfl_xor(acc, 16, 64);
    acc += __shfl_xor(acc, 32, 64);
    if (lane < 16) {
      const __hip_bfloat16 hb = __float2bfloat16(acc);
      const size_t kvb = ((size_t)r * S_DIM + s) * 8 + jj;
      if (lane < 8) k_ws[kvb] = hb; else v_ws[kvb] = hb;
    }
  }

  __shared__ float qsm[4][64];
  __shared__ float mssm[4];
  qsm[w][lane] = qacc;
  if (lane == 0) mssm[w] = macc;
  __syncthreads();
  if (w == 0) {
    const float t = qsm[0][lane] + qsm[1][lane] + qsm[2][lane] + qsm[3][lane];
    atomicAdd(&qnum[r * 64 + lane], t);
    if (lane == 0) atomicAdd(&msum[r], mssm[0] + mssm[1] + mssm[2] + mssm[3]);
  }
}

// ---------- kernel B: q projection + softmax over S + o ----------
// grid: 512 blocks (one per r), 256 threads; wave w handles heads 2w, 2w+1.
__global__ __launch_bounds__(256) void kB(
    const float* __restrict__ qnum, const float* __restrict__ msum,
    const float* __restrict__ mask, const float* __restrict__ wq,
    const __hip_bfloat16* __restrict__ k_ws,
    const __hip_bfloat16* __restrict__ v_ws, float* __restrict__ o_ws) {
  const int r = blockIdx.x;
  const int tid = threadIdx.x;
  __shared__ float qp_sm[64];
  __shared__ float q_sm[64];
  if (tid < 64) qp_sm[tid] = qnum[r * 64 + tid] / (msum[r] + EPSF);
  __syncthreads();
  if (tid < 64) {
    float a = 0.f;
#pragma unroll
    for (int c = 0; c < 64; ++c) a = fmaf(qp_sm[c], wq[c * 64 + tid], a);
    q_sm[tid] = a * 0.35355339059327373f;  // * C_HID^-0.5
  }
  __syncthreads();

  const int w = tid >> 6;
  const int lane = tid & 63;
  const int h0 = w * 2;
  float qh0[8], qh1[8];
#pragma unroll
  for (int ch = 0; ch < 8; ++ch) {
    qh0[ch] = q_sm[h0 * 8 + ch];
    qh1[ch] = q_sm[h0 * 8 + 8 + ch];
  }
  float m0 = -1e30f, l0 = 0.f, m1 = -1e30f, l1 = 0.f;
  float a0[8], a1[8];
#pragma unroll
  for (int ch = 0; ch < 8; ++ch) { a0[ch] = 0.f; a1[ch] = 0.f; }

  for (int it = 0; it < 32; ++it) {
    const int s = it * 64 + lane;
    const size_t kb = ((size_t)r * S_DIM + s) * 8;
    union { uint4 u; unsigned short us[8]; } ku, vu;
    ku.u = *reinterpret_cast<const uint4*>(&k_ws[kb]);
    vu.u = *reinterpret_cast<const uint4*>(&v_ws[kb]);
    const float bias = INFF * (mask[(size_t)s * R_DIM + r] - 1.f);
    float lg0 = bias, lg1 = bias;
#pragma unroll
    for (int ch = 0; ch < 8; ++ch) {
      const float kc = bf2f(ku.us[ch]);
      lg0 = fmaf(qh0[ch], kc, lg0);
      lg1 = fmaf(qh1[ch], kc, lg1);
    }
    const float nm0 = fmaxf(m0, lg0);
    const float c0 = __expf(m0 - nm0);
    const float p0 = __expf(lg0 - nm0);
    const float nm1 = fmaxf(m1, lg1);
    const float c1 = __expf(m1 - nm1);
    const float p1 = __expf(lg1 - nm1);
    l0 = fmaf(l0, c0, p0); m0 = nm0;
    l1 = fmaf(l1, c1, p1); m1 = nm1;
#pragma unroll
    for (int ch = 0; ch < 8; ++ch) {
      const float vc = bf2f(vu.us[ch]);
      a0[ch] = fmaf(a0[ch], c0, p0 * vc);
      a1[ch] = fmaf(a1[ch], c1, p1 * vc);
    }
  }
  // butterfly merge of online-softmax state across the 64 lanes
#pragma unroll
  for (int msk = 1; msk < 64; msk <<= 1) {
    {
      const float om = __shfl_xor(m0, msk, 64);
      const float ol = __shfl_xor(l0, msk, 64);
      const float nm = fmaxf(m0, om);
      const float ca = __expf(m0 - nm);
      const float cb = __expf(om - nm);
      l0 = l0 * ca + ol * cb;
#pragma unroll
      for (int ch = 0; ch < 8; ++ch) {
        const float oa = __shfl_xor(a0[ch], msk, 64);
        a0[ch] = a0[ch] * ca + oa * cb;
      }
      m0 = nm;
    }
    {
      const float om = __shfl_xor(m1, msk, 64);
      const float ol = __shfl_xor(l1, msk, 64);
      const float nm = fmaxf(m1, om);
      const float ca = __expf(m1 - nm);
      const float cb = __expf(om - nm);
      l1 = l1 * ca + ol * cb;
#pragma unroll
      for (int ch = 0; ch < 8; ++ch) {
        const float oa = __shfl_xor(a1[ch], msk, 64);
        a1[ch] = a1[ch] * ca + oa * cb;
      }
      m1 = nm;
    }
  }
  const float inv0 = 1.f / l0;
  const float inv1 = 1.f / l1;
#pragma unroll
  for (int ch = 0; ch < 8; ++ch) {
    if (lane == ch)     o_ws[r * 64 + h0 * 8 + ch]       = a0[ch] * inv0;
    if (lane == 8 + ch) o_ws[r * 64 + (h0 + 1) * 8 + ch] = a1[ch] * inv1;
  }
}

// ---------- kernel C: gate + output projection ----------
// grid: (S*R)/16 blocks, 256 threads (4 waves), each wave does 4 consecutive
// positions p = s*R + r (consecutive r). lane = output channel.
template <bool USE_X>
__global__ __launch_bounds__(256) void kC(
    const __hip_bfloat16* __restrict__ x_ws, const float* __restrict__ m_in,
    const float* __restrict__ ln_w, const float* __restrict__ ln_b,
    const float* __restrict__ o_ws, const float* __restrict__ wg,
    const float* __restrict__ bg, const float* __restrict__ wo,
    const float* __restrict__ bo, float* __restrict__ out) {
  const int tid = threadIdx.x;
  const int w = tid >> 6;
  const int lane = tid & 63;
  const size_t p0 = ((size_t)blockIdx.x * 4 + w) * 4;  // 4 positions per wave
  __shared__ float xsm[4][4][64];
  __shared__ float ogsm[4][4][64];

  if (USE_X) {
#pragma unroll
    for (int pp = 0; pp < 4; ++pp)
      xsm[w][pp][lane] = __bfloat162float(x_ws[(p0 + pp) * 64 + lane]);
  } else {
    const float lw = ln_w[lane];
    const float lb = ln_b[lane];
#pragma unroll
    for (int pp = 0; pp < 4; ++pp) {
      const float xv = m_in[(p0 + pp) * 64 + lane];
      const float mu = wave_sum64(xv) * (1.f / 64.f);
      const float d = xv - mu;
      const float var = wave_sum64(d * d) * (1.f / 64.f);
      xsm[w][pp][lane] = fmaf(d * rsqrtf(var + LN_EPSF), lw, lb);
    }
  }
  __syncthreads();

  // g = sigmoid(x @ wg + bg), column j = lane
  float acc[4];
  const float bgv = bg[lane];
#pragma unroll
  for (int pp = 0; pp < 4; ++pp) acc[pp] = bgv;
#pragma unroll 4
  for (int c4 = 0; c4 < 16; ++c4) {
    const float wv0 = wg[(c4 * 4 + 0) * 64 + lane];
    const float wv1 = wg[(c4 * 4 + 1) * 64 + lane];
    const float wv2 = wg[(c4 * 4 + 2) * 64 + lane];
    const float wv3 = wg[(c4 * 4 + 3) * 64 + lane];
#pragma unroll
    for (int pp = 0; pp < 4; ++pp) {
      const float4 xq = *reinterpret_cast<const float4*>(&xsm[w][pp][c4 * 4]);
      acc[pp] = fmaf(xq.x, wv0, acc[pp]);
      acc[pp] = fmaf(xq.y, wv1, acc[pp]);
      acc[pp] = fmaf(xq.z, wv2, acc[pp]);
      acc[pp] = fmaf(xq.w, wv3, acc[pp]);
    }
  }
  const int rr = (int)(p0 & (R_DIM - 1));  // p0 aligned to 4, R%4==0: no wrap
#pragma unroll
  for (int pp = 0; pp < 4; ++pp) {
    const float g = 1.f / (1.f + __expf(-acc[pp]));
    ogsm[w][pp][lane] = g * o_ws[(rr + pp) * 64 + lane];
  }
  __syncthreads();

  // out = og @ wo + bo
  float acc2[4];
  const float bov = bo[lane];
#pragma unroll
  for (int pp = 0; pp < 4; ++pp) acc2[pp] = bov;
#pragma unroll 4
  for (int j4 = 0; j4 < 16; ++j4) {
    const float wv0 = wo[(j4 * 4 + 0) * 64 + lane];
    const float wv1 = wo[(j4 * 4 + 1) * 64 + lane];
    const float wv2 = wo[(j4 * 4 + 2) * 64 + lane];
    const float wv3 = wo[(j4 * 4 + 3) * 64 + lane];
#pragma unroll
    for (int pp = 0; pp < 4; ++pp) {
      const float4 oq = *reinterpret_cast<const float4*>(&ogsm[w][pp][j4 * 4]);
      acc2[pp] = fmaf(oq.x, wv0, acc2[pp]);
      acc2[pp] = fmaf(oq.y, wv1, acc2[pp]);
      acc2[pp] = fmaf(oq.z, wv2, acc2[pp]);
      acc2[pp] = fmaf(oq.w, wv3, acc2[pp]);
    }
  }
#pragma unroll
  for (int pp = 0; pp < 4; ++pp) out[(p0 + pp) * 64 + lane] = acc2[pp];
}

// ---------- launch ----------
extern "C" void kernel_launch(void* const* d_in, const int* in_sizes, int n_in,
                              void* d_out, int out_size, void* d_ws,
                              size_t ws_size, hipStream_t stream) {
  (void)in_sizes; (void)n_in; (void)out_size;
  const float* m_in = (const float*)d_in[0];
  const float* mask = (const float*)d_in[1];
  const float* ln_w = (const float*)d_in[2];
  const float* ln_b = (const float*)d_in[3];
  const float* wq   = (const float*)d_in[4];
  const float* wk   = (const float*)d_in[5];
  const float* wv   = (const float*)d_in[6];
  const float* wg   = (const float*)d_in[7];
  const float* bg   = (const float*)d_in[8];
  const float* wo   = (const float*)d_in[9];
  const float* bo   = (const float*)d_in[10];
  float* out = (float*)d_out;
  char* ws = (char*)d_ws;

  const size_t X_BYTES  = (size_t)S_DIM * R_DIM * 64 * 2;  // 134,217,728
  const size_t KV_BYTES = (size_t)S_DIM * R_DIM * 8 * 2;   //  16,777,216
  const size_t QN_BYTES = (size_t)R_DIM * 64 * 4;          //     131,072
  const size_t MS_BYTES = (size_t)R_DIM * 4;               //       2,048
  const size_t O_BYTES  = (size_t)R_DIM * 64 * 4;          //     131,072

  const size_t need_big = X_BYTES + 2 * KV_BYTES + QN_BYTES + MS_BYTES + O_BYTES;
  const bool use_x = ws_size >= need_big;

  size_t off = use_x ? X_BYTES : 0;
  __hip_bfloat16* x_ws = (__hip_bfloat16*)ws;  // only valid if use_x
  __hip_bfloat16* k_ws = (__hip_bfloat16*)(ws + off); off += KV_BYTES;
  __hip_bfloat16* v_ws = (__hip_bfloat16*)(ws + off); off += KV_BYTES;
  float* qnum = (float*)(ws + off); off += QN_BYTES;
  float* msum = (float*)(ws + off); off += MS_BYTES;
  float* o_ws = (float*)(ws + off);

  hipMemsetAsync(qnum, 0, QN_BYTES + MS_BYTES, stream);

  const int gridA = R_DIM * (S_DIM / 32);          // 32768
  const int gridC = (S_DIM * R_DIM) / 16;          // 65536
  if (use_x) {
    kA<true><<<gridA, 256, 0, stream>>>(m_in, mask, ln_w, ln_b, wk, wv, x_ws,
                                        k_ws, v_ws, qnum, msum);
    kB<<<R_DIM, 256, 0, stream>>>(qnum, msum, mask, wq, k_ws, v_ws, o_ws);
    kC<true><<<gridC, 256, 0, stream>>>(x_ws, m_in, ln_w, ln_b, o_ws, wg, bg,
                                        wo, bo, out);
  } else {
    kA<false><<<gridA, 256, 0, stream>>>(m_in, mask, ln_w, ln_b, wk, wv, x_ws,
                                         k_ws, v_ws, qnum, msum);
    kB<<<R_DIM, 256, 0, stream>>>(qnum, msum, mask, wq, k_ws, v_ws, o_ws);
    kC<false><<<gridC, 256, 0, stream>>>(nullptr, m_in, ln_w, ln_b, o_ws, wg,
                                         bg, wo, bo, out);
  }
}

// Round 2
// 829.079 us; speedup vs baseline: 1.3754x; 1.3754x over previous
//
#include <hip/hip_runtime.h>
#include <hip/hip_bf16.h>

#define S_DIM 2048
#define R_DIM 512
#define C_DIM 64
#define LN_EPSF 1e-5f
#define EPSF 1e-10f
#define INFF 1000000000.0f

typedef __attribute__((ext_vector_type(4))) float f32x4;
typedef __attribute__((ext_vector_type(8))) short bf16x8;

// swizzled LDS byte address for a [rows][64] bf16 tile (128B rows)
__device__ __forceinline__ int SWZ(int row, int cb) {
  return row * 128 + (cb ^ ((row & 7) << 4));
}

// ---------- helpers ----------
__device__ __forceinline__ float wave_sum64(float v) {
#pragma unroll
  for (int m = 1; m < 64; m <<= 1) v += __shfl_xor(v, m, 64);
  return v;
}

__device__ __forceinline__ float bf2f(unsigned short u) {
  return __uint_as_float(((unsigned int)u) << 16);
}

// ---------- kernel W: pre-transpose weights to bf16 ----------
__global__ __launch_bounds__(256) void kW(const float* __restrict__ wg,
                                          const float* __restrict__ wo,
                                          __hip_bfloat16* __restrict__ wgT,
                                          __hip_bfloat16* __restrict__ woT) {
  const float* src = blockIdx.x ? wo : wg;
  __hip_bfloat16* dst = blockIdx.x ? woT : wgT;
  for (int idx = threadIdx.x; idx < 4096; idx += 256) {
    const int n = idx >> 6, k = idx & 63;
    dst[idx] = __float2bfloat16(src[k * 64 + n]);  // wT[n][k] = w[k][n]
  }
}

// ---------- kernel A: LN + k/v + q_pool partials (+ optional x store) ----------
template <bool STORE_X>
__global__ __launch_bounds__(256) void kA(
    const float* __restrict__ m_in, const float* __restrict__ mask,
    const float* __restrict__ ln_w, const float* __restrict__ ln_b,
    const float* __restrict__ wk, const float* __restrict__ wv,
    __hip_bfloat16* __restrict__ x_ws, __hip_bfloat16* __restrict__ k_ws,
    __hip_bfloat16* __restrict__ v_ws, float* __restrict__ qnum,
    float* __restrict__ msum) {
  const int tid = threadIdx.x;
  const int w = tid >> 6;
  const int lane = tid & 63;
  const int r = blockIdx.x & (R_DIM - 1);
  const int chunk = blockIdx.x >> 9;
  const int s_base = chunk * 32;

  const float lw = ln_w[lane];
  const float lb = ln_b[lane];

  const int j = lane & 15;
  const int q4 = lane >> 4;
  const int jj = j & 7;
  const float* wmat = (j < 8) ? wk : wv;
  float wreg[16];
#pragma unroll
  for (int cc = 0; cc < 16; ++cc) wreg[cc] = wmat[(q4 * 16 + cc) * 8 + jj];

  float qacc = 0.f;
  float macc = 0.f;

  for (int it = 0; it < 8; ++it) {
    const int s = s_base + it * 4 + w;
    const size_t pos = (size_t)s * R_DIM + r;
    const float xv = m_in[pos * 64 + lane];
    const float mk = mask[pos];
    const float mu = wave_sum64(xv) * (1.f / 64.f);
    const float d = xv - mu;
    const float var = wave_sum64(d * d) * (1.f / 64.f);
    const float xn = fmaf(d * rsqrtf(var + LN_EPSF), lw, lb);

    qacc = fmaf(xn, mk, qacc);
    macc += mk;

    if (STORE_X) x_ws[pos * 64 + lane] = __float2bfloat16(xn);

    float acc = 0.f;
#pragma unroll
    for (int cc = 0; cc < 16; ++cc) {
      const float xc = __shfl(xn, q4 * 16 + cc, 64);
      acc = fmaf(xc, wreg[cc], acc);
    }
    acc += __shfl_xor(acc, 16, 64);
    acc += __shfl_xor(acc, 32, 64);
    if (lane < 16) {
      const __hip_bfloat16 hb = __float2bfloat16(acc);
      const size_t kvb = ((size_t)r * S_DIM + s) * 8 + jj;
      if (lane < 8) k_ws[kvb] = hb; else v_ws[kvb] = hb;
    }
  }

  __shared__ float qsm[4][64];
  __shared__ float mssm[4];
  qsm[w][lane] = qacc;
  if (lane == 0) mssm[w] = macc;
  __syncthreads();
  if (w == 0) {
    const float t = qsm[0][lane] + qsm[1][lane] + qsm[2][lane] + qsm[3][lane];
    atomicAdd(&qnum[r * 64 + lane], t);
    if (lane == 0) atomicAdd(&msum[r], mssm[0] + mssm[1] + mssm[2] + mssm[3]);
  }
}

// ---------- kernel B: q projection + softmax over S + o ----------
__global__ __launch_bounds__(256) void kB(
    const float* __restrict__ qnum, const float* __restrict__ msum,
    const float* __restrict__ mask, const float* __restrict__ wq,
    const __hip_bfloat16* __restrict__ k_ws,
    const __hip_bfloat16* __restrict__ v_ws, float* __restrict__ o_ws) {
  const int r = blockIdx.x;
  const int tid = threadIdx.x;
  __shared__ float qp_sm[64];
  __shared__ float q_sm[64];
  if (tid < 64) qp_sm[tid] = qnum[r * 64 + tid] / (msum[r] + EPSF);
  __syncthreads();
  if (tid < 64) {
    float a = 0.f;
#pragma unroll
    for (int c = 0; c < 64; ++c) a = fmaf(qp_sm[c], wq[c * 64 + tid], a);
    q_sm[tid] = a * 0.35355339059327373f;
  }
  __syncthreads();

  const int w = tid >> 6;
  const int lane = tid & 63;
  const int h0 = w * 2;
  float qh0[8], qh1[8];
#pragma unroll
  for (int ch = 0; ch < 8; ++ch) {
    qh0[ch] = q_sm[h0 * 8 + ch];
    qh1[ch] = q_sm[h0 * 8 + 8 + ch];
  }
  float m0 = -1e30f, l0 = 0.f, m1 = -1e30f, l1 = 0.f;
  float a0[8], a1[8];
#pragma unroll
  for (int ch = 0; ch < 8; ++ch) { a0[ch] = 0.f; a1[ch] = 0.f; }

  for (int it = 0; it < 32; ++it) {
    const int s = it * 64 + lane;
    const size_t kb = ((size_t)r * S_DIM + s) * 8;
    union { uint4 u; unsigned short us[8]; } ku, vu;
    ku.u = *reinterpret_cast<const uint4*>(&k_ws[kb]);
    vu.u = *reinterpret_cast<const uint4*>(&v_ws[kb]);
    const float bias = INFF * (mask[(size_t)s * R_DIM + r] - 1.f);
    float lg0 = bias, lg1 = bias;
#pragma unroll
    for (int ch = 0; ch < 8; ++ch) {
      const float kc = bf2f(ku.us[ch]);
      lg0 = fmaf(qh0[ch], kc, lg0);
      lg1 = fmaf(qh1[ch], kc, lg1);
    }
    const float nm0 = fmaxf(m0, lg0);
    const float c0 = __expf(m0 - nm0);
    const float p0 = __expf(lg0 - nm0);
    const float nm1 = fmaxf(m1, lg1);
    const float c1 = __expf(m1 - nm1);
    const float p1 = __expf(lg1 - nm1);
    l0 = fmaf(l0, c0, p0); m0 = nm0;
    l1 = fmaf(l1, c1, p1); m1 = nm1;
#pragma unroll
    for (int ch = 0; ch < 8; ++ch) {
      const float vc = bf2f(vu.us[ch]);
      a0[ch] = fmaf(a0[ch], c0, p0 * vc);
      a1[ch] = fmaf(a1[ch], c1, p1 * vc);
    }
  }
#pragma unroll
  for (int msk = 1; msk < 64; msk <<= 1) {
    {
      const float om = __shfl_xor(m0, msk, 64);
      const float ol = __shfl_xor(l0, msk, 64);
      const float nm = fmaxf(m0, om);
      const float ca = __expf(m0 - nm);
      const float cb = __expf(om - nm);
      l0 = l0 * ca + ol * cb;
#pragma unroll
      for (int ch = 0; ch < 8; ++ch) {
        const float oa = __shfl_xor(a0[ch], msk, 64);
        a0[ch] = a0[ch] * ca + oa * cb;
      }
      m0 = nm;
    }
    {
      const float om = __shfl_xor(m1, msk, 64);
      const float ol = __shfl_xor(l1, msk, 64);
      const float nm = fmaxf(m1, om);
      const float ca = __expf(m1 - nm);
      const float cb = __expf(om - nm);
      l1 = l1 * ca + ol * cb;
#pragma unroll
      for (int ch = 0; ch < 8; ++ch) {
        const float oa = __shfl_xor(a1[ch], msk, 64);
        a1[ch] = a1[ch] * ca + oa * cb;
      }
      m1 = nm;
    }
  }
  const float inv0 = 1.f / l0;
  const float inv1 = 1.f / l1;
#pragma unroll
  for (int ch = 0; ch < 8; ++ch) {
    if (lane == ch)     o_ws[r * 64 + h0 * 8 + ch]       = a0[ch] * inv0;
    if (lane == 8 + ch) o_ws[r * 64 + (h0 + 1) * 8 + ch] = a1[ch] * inv1;
  }
}

// ---------- kernel C (MFMA): G = sigmoid(X@Wg+bg); OUT = (G*o)@Wo + bo ----------
// grid: P/128 blocks, 256 threads (4 waves). Each block: 128 positions.
__global__ __launch_bounds__(256) void kC_mfma(
    const __hip_bfloat16* __restrict__ x_ws, const float* __restrict__ o_ws,
    const __hip_bfloat16* __restrict__ wgT, const __hip_bfloat16* __restrict__ woT,
    const float* __restrict__ bg, const float* __restrict__ bo,
    float* __restrict__ out) {
  __shared__ __align__(16) unsigned char smem[32768];
  unsigned char* xsm  = smem;           // 16KB: X tile then og tile [128][64] bf16
  unsigned char* wg_s = smem + 16384;   // 8KB [64][64] bf16 (Wg^T)
  unsigned char* wo_s = smem + 24576;   // 8KB [64][64] bf16 (Wo^T)
  const int t = threadIdx.x;
  const int w = t >> 6;
  const int l = t & 63;
  const size_t P0 = (size_t)blockIdx.x * 128;

  // stage weights (already transposed+bf16 by kW): 512 uint4 each
  {
    const uint4* sg = (const uint4*)wgT;
    const uint4* so = (const uint4*)woT;
#pragma unroll
    for (int pp = 0; pp < 2; ++pp) {
      const int idx = pp * 256 + t;
      const int row = idx >> 3;
      const int cb = (idx & 7) * 16;
      *(uint4*)(wg_s + SWZ(row, cb)) = sg[idx];
      *(uint4*)(wo_s + SWZ(row, cb)) = so[idx];
    }
  }
  // stage X tile: 1024 uint4
  {
    const uint4* sx = (const uint4*)(x_ws + P0 * 64);
#pragma unroll
    for (int pp = 0; pp < 4; ++pp) {
      const int idx = pp * 256 + t;
      const int row = idx >> 3;
      const int cb = (idx & 7) * 16;
      *(uint4*)(xsm + SWZ(row, cb)) = sx[idx];
    }
  }
  __syncthreads();

  const int woff = w * 32;
  const int lrow = l & 15;
  const int g16 = l >> 4;

  // GEMM1: acc[mb][nb] = X(32 rows) @ Wg
  f32x4 acc[2][4] = {};
#pragma unroll
  for (int ks = 0; ks < 2; ++ks) {
    bf16x8 a[2], b[4];
#pragma unroll
    for (int mb = 0; mb < 2; ++mb)
      a[mb] = *(const bf16x8*)(xsm + SWZ(woff + mb * 16 + lrow, ks * 64 + g16 * 16));
#pragma unroll
    for (int nb = 0; nb < 4; ++nb)
      b[nb] = *(const bf16x8*)(wg_s + SWZ(nb * 16 + lrow, ks * 64 + g16 * 16));
#pragma unroll
    for (int mb = 0; mb < 2; ++mb)
#pragma unroll
      for (int nb = 0; nb < 4; ++nb)
        acc[mb][nb] = __builtin_amdgcn_mfma_f32_16x16x32_bf16(a[mb], b[nb], acc[mb][nb], 0, 0, 0);
  }
  __syncthreads();  // all A-reads of xsm done; it becomes the og tile

  // epilogue 1: og = sigmoid(acc + bg) * o[r]  -> bf16 into xsm (swizzled)
  const int r0 = (int)(P0 & (R_DIM - 1));
#pragma unroll
  for (int nb = 0; nb < 4; ++nb) {
    const int col = nb * 16 + lrow;
    const float bgv = bg[col];
#pragma unroll
    for (int mb = 0; mb < 2; ++mb) {
#pragma unroll
      for (int i = 0; i < 4; ++i) {
        const int row = woff + mb * 16 + g16 * 4 + i;
        const float gv = 1.f / (1.f + __expf(-(acc[mb][nb][i] + bgv)));
        const float og = gv * o_ws[(r0 + row) * 64 + col];
        *(__hip_bfloat16*)(xsm + SWZ(row, col * 2)) = __float2bfloat16(og);
      }
    }
  }
  __syncthreads();

  // GEMM2: acc2 = og @ Wo
  f32x4 acc2[2][4] = {};
#pragma unroll
  for (int ks = 0; ks < 2; ++ks) {
    bf16x8 a[2], b[4];
#pragma unroll
    for (int mb = 0; mb < 2; ++mb)
      a[mb] = *(const bf16x8*)(xsm + SWZ(woff + mb * 16 + lrow, ks * 64 + g16 * 16));
#pragma unroll
    for (int nb = 0; nb < 4; ++nb)
      b[nb] = *(const bf16x8*)(wo_s + SWZ(nb * 16 + lrow, ks * 64 + g16 * 16));
#pragma unroll
    for (int mb = 0; mb < 2; ++mb)
#pragma unroll
      for (int nb = 0; nb < 4; ++nb)
        acc2[mb][nb] = __builtin_amdgcn_mfma_f32_16x16x32_bf16(a[mb], b[nb], acc2[mb][nb], 0, 0, 0);
  }

  // epilogue 2: out = acc2 + bo
#pragma unroll
  for (int nb = 0; nb < 4; ++nb) {
    const int col = nb * 16 + lrow;
    const float bov = bo[col];
#pragma unroll
    for (int mb = 0; mb < 2; ++mb)
#pragma unroll
      for (int i = 0; i < 4; ++i) {
        const int row = woff + mb * 16 + g16 * 4 + i;
        out[(P0 + row) * 64 + col] = acc2[mb][nb][i] + bov;
      }
  }
}

// ---------- kernel C (fallback, VALU): gate + output projection ----------
template <bool USE_X>
__global__ __launch_bounds__(256) void kC(
    const __hip_bfloat16* __restrict__ x_ws, const float* __restrict__ m_in,
    const float* __restrict__ ln_w, const float* __restrict__ ln_b,
    const float* __restrict__ o_ws, const float* __restrict__ wg,
    const float* __restrict__ bg, const float* __restrict__ wo,
    const float* __restrict__ bo, float* __restrict__ out) {
  const int tid = threadIdx.x;
  const int w = tid >> 6;
  const int lane = tid & 63;
  const size_t p0 = ((size_t)blockIdx.x * 4 + w) * 4;
  __shared__ float xsm[4][4][64];
  __shared__ float ogsm[4][4][64];

  if (USE_X) {
#pragma unroll
    for (int pp = 0; pp < 4; ++pp)
      xsm[w][pp][lane] = __bfloat162float(x_ws[(p0 + pp) * 64 + lane]);
  } else {
    const float lw = ln_w[lane];
    const float lb = ln_b[lane];
#pragma unroll
    for (int pp = 0; pp < 4; ++pp) {
      const float xv = m_in[(p0 + pp) * 64 + lane];
      const float mu = wave_sum64(xv) * (1.f / 64.f);
      const float d = xv - mu;
      const float var = wave_sum64(d * d) * (1.f / 64.f);
      xsm[w][pp][lane] = fmaf(d * rsqrtf(var + LN_EPSF), lw, lb);
    }
  }
  __syncthreads();

  float acc[4];
  const float bgv = bg[lane];
#pragma unroll
  for (int pp = 0; pp < 4; ++pp) acc[pp] = bgv;
#pragma unroll 4
  for (int c4 = 0; c4 < 16; ++c4) {
    const float wv0 = wg[(c4 * 4 + 0) * 64 + lane];
    const float wv1 = wg[(c4 * 4 + 1) * 64 + lane];
    const float wv2 = wg[(c4 * 4 + 2) * 64 + lane];
    const float wv3 = wg[(c4 * 4 + 3) * 64 + lane];
#pragma unroll
    for (int pp = 0; pp < 4; ++pp) {
      const float4 xq = *reinterpret_cast<const float4*>(&xsm[w][pp][c4 * 4]);
      acc[pp] = fmaf(xq.x, wv0, acc[pp]);
      acc[pp] = fmaf(xq.y, wv1, acc[pp]);
      acc[pp] = fmaf(xq.z, wv2, acc[pp]);
      acc[pp] = fmaf(xq.w, wv3, acc[pp]);
    }
  }
  const int rr = (int)(p0 & (R_DIM - 1));
#pragma unroll
  for (int pp = 0; pp < 4; ++pp) {
    const float g = 1.f / (1.f + __expf(-acc[pp]));
    ogsm[w][pp][lane] = g * o_ws[(rr + pp) * 64 + lane];
  }
  __syncthreads();

  float acc2[4];
  const float bov = bo[lane];
#pragma unroll
  for (int pp = 0; pp < 4; ++pp) acc2[pp] = bov;
#pragma unroll 4
  for (int j4 = 0; j4 < 16; ++j4) {
    const float wv0 = wo[(j4 * 4 + 0) * 64 + lane];
    const float wv1 = wo[(j4 * 4 + 1) * 64 + lane];
    const float wv2 = wo[(j4 * 4 + 2) * 64 + lane];
    const float wv3 = wo[(j4 * 4 + 3) * 64 + lane];
#pragma unroll
    for (int pp = 0; pp < 4; ++pp) {
      const float4 oq = *reinterpret_cast<const float4*>(&ogsm[w][pp][j4 * 4]);
      acc2[pp] = fmaf(oq.x, wv0, acc2[pp]);
      acc2[pp] = fmaf(oq.y, wv1, acc2[pp]);
      acc2[pp] = fmaf(oq.z, wv2, acc2[pp]);
      acc2[pp] = fmaf(oq.w, wv3, acc2[pp]);
    }
  }
#pragma unroll
  for (int pp = 0; pp < 4; ++pp) out[(p0 + pp) * 64 + lane] = acc2[pp];
}

// ---------- launch ----------
extern "C" void kernel_launch(void* const* d_in, const int* in_sizes, int n_in,
                              void* d_out, int out_size, void* d_ws,
                              size_t ws_size, hipStream_t stream) {
  (void)in_sizes; (void)n_in; (void)out_size;
  const float* m_in = (const float*)d_in[0];
  const float* mask = (const float*)d_in[1];
  const float* ln_w = (const float*)d_in[2];
  const float* ln_b = (const float*)d_in[3];
  const float* wq   = (const float*)d_in[4];
  const float* wk   = (const float*)d_in[5];
  const float* wv   = (const float*)d_in[6];
  const float* wg   = (const float*)d_in[7];
  const float* bg   = (const float*)d_in[8];
  const float* wo   = (const float*)d_in[9];
  const float* bo   = (const float*)d_in[10];
  float* out = (float*)d_out;
  char* ws = (char*)d_ws;

  const size_t X_BYTES  = (size_t)S_DIM * R_DIM * 64 * 2;
  const size_t KV_BYTES = (size_t)S_DIM * R_DIM * 8 * 2;
  const size_t QN_BYTES = (size_t)R_DIM * 64 * 4;
  const size_t MS_BYTES = (size_t)R_DIM * 4;
  const size_t O_BYTES  = (size_t)R_DIM * 64 * 4;
  const size_t WT_BYTES = 64 * 64 * 2;  // 8KB each transposed weight

  const size_t need_big =
      X_BYTES + 2 * KV_BYTES + QN_BYTES + MS_BYTES + O_BYTES + 2 * WT_BYTES;
  const bool use_x = ws_size >= need_big;

  size_t off = use_x ? X_BYTES : 0;
  __hip_bfloat16* x_ws = (__hip_bfloat16*)ws;
  __hip_bfloat16* k_ws = (__hip_bfloat16*)(ws + off); off += KV_BYTES;
  __hip_bfloat16* v_ws = (__hip_bfloat16*)(ws + off); off += KV_BYTES;
  float* qnum = (float*)(ws + off); off += QN_BYTES;
  float* msum = (float*)(ws + off); off += MS_BYTES;
  float* o_ws = (float*)(ws + off); off += O_BYTES;
  __hip_bfloat16* wgT = (__hip_bfloat16*)(ws + off); off += WT_BYTES;
  __hip_bfloat16* woT = (__hip_bfloat16*)(ws + off);

  hipMemsetAsync(qnum, 0, QN_BYTES + MS_BYTES, stream);

  const int gridA = R_DIM * (S_DIM / 32);
  if (use_x) {
    kW<<<2, 256, 0, stream>>>(wg, wo, wgT, woT);
    kA<true><<<gridA, 256, 0, stream>>>(m_in, mask, ln_w, ln_b, wk, wv, x_ws,
                                        k_ws, v_ws, qnum, msum);
    kB<<<R_DIM, 256, 0, stream>>>(qnum, msum, mask, wq, k_ws, v_ws, o_ws);
    const int gridC = (S_DIM * R_DIM) / 128;  // 8192
    kC_mfma<<<gridC, 256, 0, stream>>>(x_ws, o_ws, wgT, woT, bg, bo, out);
  } else {
    kA<false><<<gridA, 256, 0, stream>>>(m_in, mask, ln_w, ln_b, wk, wv, x_ws,
                                         k_ws, v_ws, qnum, msum);
    kB<<<R_DIM, 256, 0, stream>>>(qnum, msum, mask, wq, k_ws, v_ws, o_ws);
    const int gridC = (S_DIM * R_DIM) / 16;
    kC<false><<<gridC, 256, 0, stream>>>(nullptr, m_in, ln_w, ln_b, o_ws, wg,
                                         bg, wo, bo, out);
  }
}